// Round 1
// baseline (2121.107 us; speedup 1.0000x reference)
//
#include <hip/hip_runtime.h>

#define TOKENS 4096
#define DIN    4096
#define DOUT   16384

#define BM 128
#define BN 128
#define BK 32
#define LDSS 40   // padded LDS row stride (bf16 elems): 80 B -> frag reads 2-way (free)

typedef __attribute__((ext_vector_type(8))) short short8;
typedef __attribute__((ext_vector_type(4))) float f32x4;

// fp32 -> bf16 bits, round-to-nearest-even (inputs are finite/normal)
__device__ __forceinline__ unsigned short f2bf(float f) {
    unsigned u = __builtin_bit_cast(unsigned, f);
    u += 0x7fffu + ((u >> 16) & 1u);
    return (unsigned short)(u >> 16);
}

__global__ __launch_bounds__(256, 2)
void QuantizedLinear_8667244003662_kernel(const float* __restrict__ x,
                                          const int*   __restrict__ qw,
                                          const float* __restrict__ scale,
                                          const float* __restrict__ bias,
                                          float*       __restrict__ out) {
    __shared__ unsigned short As[BM * LDSS];
    __shared__ unsigned short Bs[BN * LDSS];

    const int tid  = threadIdx.x;
    const int lane = tid & 63;
    const int wave = tid >> 6;
    const int wm   = wave >> 1;   // wave row (0..1) -> 64 rows of M
    const int wn   = wave & 1;    // wave col (0..1) -> 64 cols of N
    const int quad = lane >> 4;   // 0..3
    const int l16  = lane & 15;

    const int m0 = blockIdx.x * BM;   // m fastest-varying: 32 blocks share a qw slab
    const int n0 = blockIdx.y * BN;

    // staging geometry: tile row (32 elems) = 8 threads x 4 elems
    const int srow = tid >> 3;        // 0..31
    const int scol = (tid & 7) * 4;   // 0,4,...,28

    f32x4 acc[4][4];
    #pragma unroll
    for (int i = 0; i < 4; ++i)
        #pragma unroll
        for (int j = 0; j < 4; ++j)
            acc[i][j] = (f32x4){0.f, 0.f, 0.f, 0.f};

    for (int k0 = 0; k0 < DIN; k0 += BK) {
        __syncthreads();
        // ---- stage A: 128x32 fp32 -> bf16 in LDS ----
        #pragma unroll
        for (int p = 0; p < 4; ++p) {
            const int r = p * 32 + srow;
            const float4 v = *(const float4*)&x[(m0 + r) * DIN + k0 + scol];
            const unsigned a01 = (unsigned)f2bf(v.x) | ((unsigned)f2bf(v.y) << 16);
            const unsigned a23 = (unsigned)f2bf(v.z) | ((unsigned)f2bf(v.w) << 16);
            *(unsigned long long*)&As[r * LDSS + scol] =
                (unsigned long long)a01 | ((unsigned long long)a23 << 32);
        }
        // ---- stage B: 128x32 int32 -> bf16 in LDS (int8 values, exact in bf16) ----
        #pragma unroll
        for (int p = 0; p < 4; ++p) {
            const int r = p * 32 + srow;
            const int4 v = *(const int4*)&qw[(n0 + r) * DIN + k0 + scol];
            const unsigned b01 = (unsigned)f2bf((float)v.x) | ((unsigned)f2bf((float)v.y) << 16);
            const unsigned b23 = (unsigned)f2bf((float)v.z) | ((unsigned)f2bf((float)v.w) << 16);
            *(unsigned long long*)&Bs[r * LDSS + scol] =
                (unsigned long long)b01 | ((unsigned long long)b23 << 32);
        }
        __syncthreads();

        // ---- fragments: A[m=l16][k=quad*8+j], B[n=l16][k=quad*8+j] ----
        short8 af[4], bfv[4];
        #pragma unroll
        for (int i = 0; i < 4; ++i)
            af[i] = *(const short8*)&As[(wm * 64 + i * 16 + l16) * LDSS + quad * 8];
        #pragma unroll
        for (int j = 0; j < 4; ++j)
            bfv[j] = *(const short8*)&Bs[(wn * 64 + j * 16 + l16) * LDSS + quad * 8];

        #pragma unroll
        for (int i = 0; i < 4; ++i)
            #pragma unroll
            for (int j = 0; j < 4; ++j)
                acc[i][j] = __builtin_amdgcn_mfma_f32_16x16x32_bf16(af[i], bfv[j], acc[i][j], 0, 0, 0);
    }

    // ---- epilogue: C/D layout col=l16, row=quad*4+r; fuse scale+bias ----
    #pragma unroll
    for (int j = 0; j < 4; ++j) {
        const int col = n0 + wn * 64 + j * 16 + l16;
        const float s = scale[col];
        const float b = bias[col];
        #pragma unroll
        for (int i = 0; i < 4; ++i) {
            const int row0 = m0 + wm * 64 + i * 16 + quad * 4;
            #pragma unroll
            for (int r = 0; r < 4; ++r)
                out[(row0 + r) * DOUT + col] = acc[i][j][r] * s + b;
        }
    }
}

extern "C" void kernel_launch(void* const* d_in, const int* in_sizes, int n_in,
                              void* d_out, int out_size, void* d_ws, size_t ws_size,
                              hipStream_t stream) {
    const float* x     = (const float*)d_in[0];
    const int*   qw    = (const int*)d_in[1];   // int8 values stored as int32 per harness
    const float* scale = (const float*)d_in[2];
    const float* bias  = (const float*)d_in[3];
    float*       out   = (float*)d_out;

    dim3 grid(TOKENS / BM, DOUT / BN);  // (32, 128); m fastest for qw L2 reuse
    dim3 block(256);
    QuantizedLinear_8667244003662_kernel<<<grid, block, 0, stream>>>(x, qw, scale, bias, out);
}

// Round 2
// 1085.457 us; speedup vs baseline: 1.9541x; 1.9541x over previous
//
#include <hip/hip_runtime.h>

#define TOKENS 4096
#define DIN    4096
#define DOUT   16384

#define BM 128
#define BN 128
#define BK 32

#define X_BYTES ((size_t)TOKENS * DIN * 2)   // 32 MB bf16
#define W_BYTES ((size_t)DOUT   * DIN * 2)   // 128 MB bf16

typedef __attribute__((ext_vector_type(8))) short short8;
typedef __attribute__((ext_vector_type(4))) float f32x4;

// fp32 -> bf16 bits, round-to-nearest-even (inputs finite)
__device__ __forceinline__ unsigned short f2bf(float f) {
    unsigned u = __builtin_bit_cast(unsigned, f);
    u += 0x7fffu + ((u >> 16) & 1u);
    return (unsigned short)(u >> 16);
}

#define GLOAD_LDS16(gptr, lptr)                                                        \
    __builtin_amdgcn_global_load_lds(                                                  \
        (const __attribute__((address_space(1))) unsigned int*)(gptr),                 \
        (__attribute__((address_space(3))) unsigned int*)(lptr), 16, 0, 0)

// ---------------- pre-pass converters (memory-bound) ----------------
__global__ __launch_bounds__(256)
void cvt_x_kernel(const float* __restrict__ in, unsigned short* __restrict__ out) {
    const size_t base = ((size_t)blockIdx.x * 256 + threadIdx.x) * 8;
    const float4 a = *(const float4*)&in[base];
    const float4 b = *(const float4*)&in[base + 4];
    uint4 o;
    o.x = (unsigned)f2bf(a.x) | ((unsigned)f2bf(a.y) << 16);
    o.y = (unsigned)f2bf(a.z) | ((unsigned)f2bf(a.w) << 16);
    o.z = (unsigned)f2bf(b.x) | ((unsigned)f2bf(b.y) << 16);
    o.w = (unsigned)f2bf(b.z) | ((unsigned)f2bf(b.w) << 16);
    *(uint4*)&out[base] = o;
}

__global__ __launch_bounds__(256)
void cvt_w_kernel(const int* __restrict__ in, unsigned short* __restrict__ out) {
    const size_t base = ((size_t)blockIdx.x * 256 + threadIdx.x) * 8;
    const int4 a = *(const int4*)&in[base];
    const int4 b = *(const int4*)&in[base + 4];
    uint4 o;   // int8 values are exact in bf16
    o.x = (unsigned)f2bf((float)a.x) | ((unsigned)f2bf((float)a.y) << 16);
    o.y = (unsigned)f2bf((float)a.z) | ((unsigned)f2bf((float)a.w) << 16);
    o.z = (unsigned)f2bf((float)b.x) | ((unsigned)f2bf((float)b.y) << 16);
    o.w = (unsigned)f2bf((float)b.z) | ((unsigned)f2bf((float)b.w) << 16);
    *(uint4*)&out[base] = o;
}

// ---------------- m97-style bf16 GEMM with global_load_lds ----------------
// LDS tile: 128 rows x 32 bf16 (64 B = 4 chunks of 16 B per row), 512 chunks.
// XOR swizzle: phys chunk (row, pq) holds global chunk (row, pq ^ ((row>>1)&3)).
// Frag ds_read_b128: each of 32 banks hit by exactly 2 lanes -> conflict-free.
__global__ __launch_bounds__(256, 2)
void gemm_bf16_kernel(const unsigned short* __restrict__ xa,   // [TOKENS][DIN] bf16
                      const unsigned short* __restrict__ wb,   // [DOUT][DIN]  bf16
                      const float* __restrict__ scale,
                      const float* __restrict__ bias,
                      float* __restrict__ out) {
    __shared__ unsigned short As[BM * BK];   // 8 KB
    __shared__ unsigned short Bs[BN * BK];   // 8 KB

    const int tid  = threadIdx.x;
    const int lane = tid & 63;
    const int wave = tid >> 6;
    const int wm   = wave >> 1;
    const int wn   = wave & 1;
    const int quad = lane >> 4;
    const int l16  = lane & 15;

    const int m0 = blockIdx.x * BM;   // m fastest-varying
    const int n0 = blockIdx.y * BN;

    // ---- staging addresses: issue i in {0,1}, thread handles phys chunk p = i*256+tid ----
    // global source for phys chunk p: row = p>>2, gq = (p&3) ^ ((row>>1)&3)
    size_t ga[2], gb[2];
    #pragma unroll
    for (int i = 0; i < 2; ++i) {
        const int p    = i * 256 + tid;
        const int row  = p >> 2;
        const int gq   = (p & 3) ^ ((row >> 1) & 3);
        ga[i] = (size_t)(m0 + row) * DIN + gq * 8;   // bf16 elem offset (k0 added in loop)
        gb[i] = (size_t)(n0 + row) * DIN + gq * 8;
    }
    // wave-uniform LDS bases for global_load_lds (lane writes base + lane*16)
    unsigned short* lA[2];
    unsigned short* lB[2];
    #pragma unroll
    for (int i = 0; i < 2; ++i) {
        const int chunk0 = i * 256 + wave * 64;
        lA[i] = &As[chunk0 * 8];
        lB[i] = &Bs[chunk0 * 8];
    }

    // ---- fragment LDS addresses (iteration-invariant, swizzled) ----
    int aoff[4], boff[4];
    #pragma unroll
    for (int i = 0; i < 4; ++i) {
        const int rowA = wm * 64 + i * 16 + l16;
        aoff[i] = (rowA * 4 + (quad ^ ((rowA >> 1) & 3))) * 8;   // bf16 elems
        const int rowB = wn * 64 + i * 16 + l16;
        boff[i] = (rowB * 4 + (quad ^ ((rowB >> 1) & 3))) * 8;
    }

    f32x4 acc[4][4];
    #pragma unroll
    for (int i = 0; i < 4; ++i)
        #pragma unroll
        for (int j = 0; j < 4; ++j)
            acc[i][j] = (f32x4){0.f, 0.f, 0.f, 0.f};

    for (int k0 = 0; k0 < DIN; k0 += BK) {
        __syncthreads();   // previous iter's ds_reads complete before overwrite
        GLOAD_LDS16(xa + ga[0] + k0, lA[0]);
        GLOAD_LDS16(xa + ga[1] + k0, lA[1]);
        GLOAD_LDS16(wb + gb[0] + k0, lB[0]);
        GLOAD_LDS16(wb + gb[1] + k0, lB[1]);
        __syncthreads();   // vmcnt(0) drain -> tiles visible

        short8 af[4], bfv[4];
        #pragma unroll
        for (int i = 0; i < 4; ++i) af[i]  = *(const short8*)&As[aoff[i]];
        #pragma unroll
        for (int j = 0; j < 4; ++j) bfv[j] = *(const short8*)&Bs[boff[j]];

        #pragma unroll
        for (int i = 0; i < 4; ++i)
            #pragma unroll
            for (int j = 0; j < 4; ++j)
                acc[i][j] = __builtin_amdgcn_mfma_f32_16x16x32_bf16(af[i], bfv[j], acc[i][j], 0, 0, 0);
    }

    // ---- epilogue: C/D col=l16 (n), row=quad*4+r (m); fuse scale+bias ----
    #pragma unroll
    for (int j = 0; j < 4; ++j) {
        const int col = n0 + wn * 64 + j * 16 + l16;
        const float s = scale[col];
        const float b = bias[col];
        #pragma unroll
        for (int i = 0; i < 4; ++i) {
            const int row0 = m0 + wm * 64 + i * 16 + quad * 4;
            #pragma unroll
            for (int r = 0; r < 4; ++r)
                out[(size_t)(row0 + r) * DOUT + col] = acc[i][j][r] * s + b;
        }
    }
}

// ---------------- fallback (round-1 kernel, used only if ws too small) ----------------
#define LDSS 40
__global__ __launch_bounds__(256, 2)
void gemm_fallback_kernel(const float* __restrict__ x, const int* __restrict__ qw,
                          const float* __restrict__ scale, const float* __restrict__ bias,
                          float* __restrict__ out) {
    __shared__ unsigned short As[BM * LDSS];
    __shared__ unsigned short Bs[BN * LDSS];
    const int tid = threadIdx.x, lane = tid & 63, wave = tid >> 6;
    const int wm = wave >> 1, wn = wave & 1, quad = lane >> 4, l16 = lane & 15;
    const int m0 = blockIdx.x * BM, n0 = blockIdx.y * BN;
    const int srow = tid >> 3, scol = (tid & 7) * 4;
    f32x4 acc[4][4];
    #pragma unroll
    for (int i = 0; i < 4; ++i)
        #pragma unroll
        for (int j = 0; j < 4; ++j) acc[i][j] = (f32x4){0.f, 0.f, 0.f, 0.f};
    for (int k0 = 0; k0 < DIN; k0 += BK) {
        __syncthreads();
        #pragma unroll
        for (int p = 0; p < 4; ++p) {
            const int r = p * 32 + srow;
            const float4 v = *(const float4*)&x[(size_t)(m0 + r) * DIN + k0 + scol];
            const unsigned a01 = (unsigned)f2bf(v.x) | ((unsigned)f2bf(v.y) << 16);
            const unsigned a23 = (unsigned)f2bf(v.z) | ((unsigned)f2bf(v.w) << 16);
            *(unsigned long long*)&As[r * LDSS + scol] =
                (unsigned long long)a01 | ((unsigned long long)a23 << 32);
        }
        #pragma unroll
        for (int p = 0; p < 4; ++p) {
            const int r = p * 32 + srow;
            const int4 v = *(const int4*)&qw[(size_t)(n0 + r) * DIN + k0 + scol];
            const unsigned b01 = (unsigned)f2bf((float)v.x) | ((unsigned)f2bf((float)v.y) << 16);
            const unsigned b23 = (unsigned)f2bf((float)v.z) | ((unsigned)f2bf((float)v.w) << 16);
            *(unsigned long long*)&Bs[r * LDSS + scol] =
                (unsigned long long)b01 | ((unsigned long long)b23 << 32);
        }
        __syncthreads();
        short8 af[4], bfv[4];
        #pragma unroll
        for (int i = 0; i < 4; ++i)
            af[i] = *(const short8*)&As[(wm * 64 + i * 16 + l16) * LDSS + quad * 8];
        #pragma unroll
        for (int j = 0; j < 4; ++j)
            bfv[j] = *(const short8*)&Bs[(wn * 64 + j * 16 + l16) * LDSS + quad * 8];
        #pragma unroll
        for (int i = 0; i < 4; ++i)
            #pragma unroll
            for (int j = 0; j < 4; ++j)
                acc[i][j] = __builtin_amdgcn_mfma_f32_16x16x32_bf16(af[i], bfv[j], acc[i][j], 0, 0, 0);
    }
    #pragma unroll
    for (int j = 0; j < 4; ++j) {
        const int col = n0 + wn * 64 + j * 16 + l16;
        const float s = scale[col], b = bias[col];
        #pragma unroll
        for (int i = 0; i < 4; ++i) {
            const int row0 = m0 + wm * 64 + i * 16 + quad * 4;
            #pragma unroll
            for (int r = 0; r < 4; ++r)
                out[(size_t)(row0 + r) * DOUT + col] = acc[i][j][r] * s + b;
        }
    }
}

extern "C" void kernel_launch(void* const* d_in, const int* in_sizes, int n_in,
                              void* d_out, int out_size, void* d_ws, size_t ws_size,
                              hipStream_t stream) {
    const float* x     = (const float*)d_in[0];
    const int*   qw    = (const int*)d_in[1];
    const float* scale = (const float*)d_in[2];
    const float* bias  = (const float*)d_in[3];
    float*       out   = (float*)d_out;

    if (ws_size >= X_BYTES + W_BYTES) {
        unsigned short* x_bf = (unsigned short*)d_ws;
        unsigned short* w_bf = (unsigned short*)((char*)d_ws + X_BYTES);
        cvt_x_kernel<<<dim3((TOKENS * DIN) / (256 * 8)), dim3(256), 0, stream>>>(x, x_bf);
        cvt_w_kernel<<<dim3((DOUT * DIN) / (256 * 8)), dim3(256), 0, stream>>>(qw, w_bf);
        gemm_bf16_kernel<<<dim3(TOKENS / BM, DOUT / BN), dim3(256), 0, stream>>>(
            x_bf, w_bf, scale, bias, out);
    } else {
        gemm_fallback_kernel<<<dim3(TOKENS / BM, DOUT / BN), dim3(256), 0, stream>>>(
            x, qw, scale, bias, out);
    }
}